// Round 3
// baseline (1335.941 us; speedup 1.0000x reference)
//
#include <hip/hip_runtime.h>
#include <hip/hip_cooperative_groups.h>
#include <math.h>

namespace cg = cooperative_groups;

// Problem: B=16, N=2049, C=1024, w_qkv is (1024, 3072) row-major.
// out = softmax over n of  scale * (x[b,0,:] @ Wq) . (x[b,n+1,:] @ Wk)
// Reassociated: q_cls[b] = Wq^T x[b,0,:];  v[b] = Wk @ q_cls[b];
//               logit[b,n] = scale * x[b,n+1,:] . v[b]
//
// Structure (this round): 2 dispatches.
//  D1 cooperative (grid 256 x 256): qcls partials -> grid.sync -> reduce
//     -> grid.sync -> v.  Keeps baseline per-stage parallelism (round-2
//     lesson: 32-block K1 fusion starved the 4MB Wq read).
//  D2 (grid 8192 x 256): logits stream + last-block-per-batch softmax
//     (release fence + atomicAdd + acquire fence; cnt zeroed by D1).

#define BATCH 16
#define SEQ   2049
#define CH    1024
#define W3    3072
#define NOUT  2048

// ws layout (floats):
//   part   : [0, 64*16*1024) = 1048576   (4 MB)
//   qcls   : [1048576, +16384)
//   v      : [1064960, +16384)
//   logits : [1081344, +32768)
//   cnt    : [1114112, +16)  (ints, zeroed by D1 every launch)

// ---------------- D1: cooperative qcls -> reduce -> v ----------------
__global__ __launch_bounds__(256) void prep_kernel(
    const float* __restrict__ x, const float* __restrict__ w,
    float* __restrict__ part, float* __restrict__ qcls,
    float* __restrict__ v, int* __restrict__ cnt) {
    cg::grid_group grid = cg::this_grid();
    const int bid  = blockIdx.x;       // 0..255
    const int t    = threadIdx.x;
    const int lane = t & 63;
    const int wv   = t >> 6;           // 0..3

    if (bid == 0 && t < BATCH) cnt[t] = 0;   // reset D2 completion counters

    __shared__ float  xs[BATCH][16];         // 1 KB   (phase 1)
    __shared__ float4 red[4][8][64];         // 32 KB  (phase 1)
    __shared__ float  qs[BATCH * CH];        // 64 KB  (phase 3)

    // ---- Phase 1: q_cls partials. Block = (ci, pi): Wq tile
    // [pi*16, +16) x [ci*256, +256); wave w owns 4 rows; 4-wave LDS
    // reduce -> 64 cross-block partials (same layout/traffic as the
    // measured-fast baseline K1).
    {
        const int ci = bid & 3;
        const int pi = bid >> 2;       // 0..63
        {
            const int b = t >> 4, dd = t & 15;   // t covers 16*16 exactly
            xs[b][dd] = x[(size_t)b * SEQ * CH + pi * 16 + dd];
        }
        __syncthreads();

        const int c = ci * 256 + lane * 4;
        float4 acc[BATCH];
        #pragma unroll
        for (int b = 0; b < BATCH; ++b) acc[b] = {0.f, 0.f, 0.f, 0.f};

        const int drow0 = pi * 16 + wv * 4;
        #pragma unroll
        for (int dd = 0; dd < 4; ++dd) {
            const float4 wvec = *(const float4*)(w + (size_t)(drow0 + dd) * W3 + c);
            const int dl = wv * 4 + dd;
            #pragma unroll
            for (int b = 0; b < BATCH; ++b) {
                const float s = xs[b][dl];
                acc[b].x += s * wvec.x; acc[b].y += s * wvec.y;
                acc[b].z += s * wvec.z; acc[b].w += s * wvec.w;
            }
        }
        // 4-wave reduce, 2 passes of 8 batches; wave w owns batches w*2,w*2+1.
        #pragma unroll
        for (int p = 0; p < 2; ++p) {
            __syncthreads();
            #pragma unroll
            for (int b2 = 0; b2 < 8; ++b2)
                red[wv][b2][lane] = acc[p * 8 + b2];
            __syncthreads();
            #pragma unroll
            for (int k = 0; k < 2; ++k) {
                const int b2 = wv * 2 + k;
                float4 s = red[0][b2][lane];
                #pragma unroll
                for (int ww = 1; ww < 4; ++ww) {
                    const float4 r = red[ww][b2][lane];
                    s.x += r.x; s.y += r.y; s.z += r.z; s.w += r.w;
                }
                *(float4*)(part + ((size_t)pi * BATCH + p * 8 + b2) * CH + c) = s;
            }
        }
    }
    __threadfence();          // agent-scope release (cross-XCD L2 writeback)
    grid.sync();

    // ---- Phase 2: reduce 64 partials -> qcls (blocks 0..63, coalesced).
    if (bid < 64) {
        const int id = bid * 256 + t;            // b*1024 + c
        float s = 0.f;
        #pragma unroll 8
        for (int p = 0; p < 64; ++p) s += part[(size_t)p * BATCH * CH + id];
        qcls[id] = s;
    }
    __threadfence();
    grid.sync();

    // ---- Phase 3: v[b,d] = Wk[d,:] . q_cls[b,:]. One Wk row per wave.
    {
        const float4* q4 = (const float4*)qcls;
        for (int i4 = t; i4 < BATCH * CH / 4; i4 += 256)
            ((float4*)qs)[i4] = q4[i4];
        __syncthreads();

        const int d = bid * 4 + wv;              // 0..1023
        const float* wrow = w + (size_t)d * W3 + CH;   // Wk = cols [1024,2048)
        float4 wv4[4];
        #pragma unroll
        for (int j = 0; j < 4; ++j)
            wv4[j] = *(const float4*)(wrow + lane * 4 + j * 256);
        #pragma unroll
        for (int b = 0; b < BATCH; ++b) {
            float acc = 0.f;
            #pragma unroll
            for (int j = 0; j < 4; ++j) {
                const float4 qv = *(const float4*)(&qs[b * CH + lane * 4 + j * 256]);
                acc += wv4[j].x * qv.x + wv4[j].y * qv.y
                     + wv4[j].z * qv.z + wv4[j].w * qv.w;
            }
            #pragma unroll
            for (int off = 32; off > 0; off >>= 1)
                acc += __shfl_down(acc, off, 64);
            if (lane == 0) v[b * CH + d] = acc;
        }
    }
}

// ---------------- D2: logits stream + last-block softmax ----------------
// grid 8192 x 256. Block = 4 rows of ONE batch (2048 % 4 == 0); v[b] staged
// in LDS. After logits, release-fence + atomicAdd(cnt[b]); the 512th block
// of a batch acquire-fences and runs that batch's softmax (8 KB from L2/L3).
__global__ __launch_bounds__(256) void logits_softmax_kernel(
    const float* __restrict__ x, const float* __restrict__ v,
    float* __restrict__ logits, int* __restrict__ cnt,
    float* __restrict__ out) {
    const int t = threadIdx.x;
    const int lane = t & 63;
    const int row0 = blockIdx.x * 4;
    const int b = row0 >> 11;          // constant within block

    __shared__ float4 vs[CH / 4];      // 4 KB
    vs[t] = ((const float4*)(v + (size_t)b * CH))[t];
    __syncthreads();

    const int row = row0 + (t >> 6);
    const int n = row & (NOUT - 1);
    const float* xrow = x + ((size_t)b * SEQ + n + 1) * CH;
    float acc = 0.f;
    #pragma unroll
    for (int j = 0; j < 4; ++j) {
        const float4 xv = *(const float4*)(xrow + lane * 4 + j * 256);
        const float4 vv = vs[lane + j * 64];
        acc += xv.x * vv.x + xv.y * vv.y + xv.z * vv.z + xv.w * vv.w;
    }
    #pragma unroll
    for (int off = 32; off > 0; off >>= 1)
        acc += __shfl_down(acc, off, 64);
    if (lane == 0) logits[row] = acc * 0.03125f;   // scale = C^-0.5 = 1/32

    // completion protocol (device-scope release/acquire; no spin, no hang)
    __threadfence();
    __shared__ int lastf;
    __syncthreads();
    if (t == 0) lastf = (atomicAdd(&cnt[b], 1) == (NOUT / 4 - 1));
    __syncthreads();
    if (!lastf) return;
    __threadfence();

    // softmax for batch b
    __shared__ float sm[256];
    float val[8];
    float m = -1e30f;
    #pragma unroll
    for (int i = 0; i < 8; ++i) {
        val[i] = logits[b * NOUT + t + i * 256];
        m = fmaxf(m, val[i]);
    }
    sm[t] = m; __syncthreads();
    for (int s = 128; s > 0; s >>= 1) {
        if (t < s) sm[t] = fmaxf(sm[t], sm[t + s]);
        __syncthreads();
    }
    const float mx = sm[0];
    __syncthreads();
    float e[8];
    float sum = 0.f;
    #pragma unroll
    for (int i = 0; i < 8; ++i) { e[i] = expf(val[i] - mx); sum += e[i]; }
    sm[t] = sum; __syncthreads();
    for (int s = 128; s > 0; s >>= 1) {
        if (t < s) sm[t] += sm[t + s];
        __syncthreads();
    }
    const float inv = 1.0f / sm[0];
    #pragma unroll
    for (int i = 0; i < 8; ++i) out[b * NOUT + t + i * 256] = e[i] * inv;
}

extern "C" void kernel_launch(void* const* d_in, const int* in_sizes, int n_in,
                              void* d_out, int out_size, void* d_ws, size_t ws_size,
                              hipStream_t stream) {
    const float* x = (const float*)d_in[0];   // (16, 2049, 1024) fp32
    const float* w = (const float*)d_in[1];   // (1024, 3072) fp32
    float* out = (float*)d_out;               // (16, 2048) fp32
    float* ws = (float*)d_ws;

    float* part   = ws;                        // 4 MB
    float* qcls   = ws + 1048576;
    float* vbuf   = ws + 1064960;
    float* logits = ws + 1081344;
    int*   cnt    = (int*)(ws + 1114112);

    void* args[] = {(void*)&x, (void*)&w, (void*)&part, (void*)&qcls,
                    (void*)&vbuf, (void*)&cnt};
    hipLaunchCooperativeKernel((const void*)prep_kernel, dim3(256), dim3(256),
                               args, 0, stream);
    logits_softmax_kernel<<<8192, 256, 0, stream>>>(x, vbuf, logits, cnt, out);
}

// Round 4
// 224.551 us; speedup vs baseline: 5.9494x; 5.9494x over previous
//
#include <hip/hip_runtime.h>
#include <math.h>

// Problem: B=16, N=2049, C=1024, w_qkv is (1024, 3072) row-major.
// out = softmax over n of  scale * (x[b,0,:] @ Wq) . (x[b,n+1,:] @ Wk)
// Reassociated: q_cls[b] = Wq^T x[b,0,:];  v[b] = Wk @ q_cls[b];
//               logit[b,n] = scale * x[b,n+1,:] . v[b]
//
// Round-3 lesson: device-scope fences in a wide grid serialize the chip
// (1056us @ 0.8% BW). Round-2 lesson: don't collapse grid parallelism to
// save a dispatch. This round: 4 dispatches, no atomics/fences/coop.
// K1' computes q_cls DIRECTLY (no partials, no reduce dispatch): each block
// owns 16 complete columns of Wq; lane = (batch, col-quad); 8 waves split
// the 1024-row range; one tiny LDS reduce at the end.

#define BATCH 16
#define SEQ   2049
#define CH    1024
#define W3    3072
#define NOUT  2048
#define XSTR  1028   // xs stride (CH+4): 2-way-max LDS banking, 16B aligned

// ws layout (floats):
//   qcls   : [0, 16384)
//   v      : [16384, +16384)
//   logits : [32768, +32768)

// ---------------- K1': q_cls direct ----------------
// grid 64, block 512 (8 waves). Block ci owns cols [ci*16, +16).
// lane = b*4 + cc  (16 batches x 4 float4-cols = 64 lanes exactly).
// Wave wv accumulates rows [wv*128, +128); LDS reduce across waves.
// Wq read exactly once chip-wide (4 MB) in 64B row-segments.
__global__ __launch_bounds__(512) void qcls_kernel(
    const float* __restrict__ x, const float* __restrict__ w,
    float* __restrict__ qcls) {
    const int ci = blockIdx.x;            // 0..63
    const int t  = threadIdx.x;
    const int lane = t & 63;
    const int wv   = t >> 6;              // 0..7

    __shared__ float  xs[BATCH * XSTR];   // ~65.8 KB: xs[b*XSTR + d]
    __shared__ float4 red[8][64];         // 8 KB

    // stage x_cls for all batches (coalesced float4)
    const float4* x4 = (const float4*)x;
    for (int i4 = t; i4 < BATCH * CH / 4; i4 += 512) {
        const int b = i4 >> 8, d4 = i4 & 255;
        *(float4*)(xs + b * XSTR + d4 * 4) = x4[(size_t)b * (SEQ * CH / 4) + d4];
    }
    __syncthreads();

    const int b  = lane >> 2;             // 0..15
    const int cc = lane & 3;              // 0..3
    const int c  = ci * 16 + cc * 4;      // column quad (< 1024 = Wq range)

    float4 acc = {0.f, 0.f, 0.f, 0.f};
    const int d0 = wv * 128;
    #pragma unroll 8
    for (int dd = 0; dd < 128; ++dd) {
        const int d = d0 + dd;
        const float4 wvec = *(const float4*)(w + (size_t)d * W3 + c);
        const float  s    = xs[b * XSTR + d];
        acc.x += s * wvec.x; acc.y += s * wvec.y;
        acc.z += s * wvec.z; acc.w += s * wvec.w;
    }
    red[wv][lane] = acc;
    __syncthreads();

    if (t < 64) {
        float4 s = red[0][t];
        #pragma unroll
        for (int ww = 1; ww < 8; ++ww) {
            const float4 r = red[ww][t];
            s.x += r.x; s.y += r.y; s.z += r.z; s.w += r.w;
        }
        *(float4*)(qcls + (t >> 2) * CH + ci * 16 + (t & 3) * 4) = s;
    }
}

// ---------------- K2: v[b,d] = Wk[d,:] . q_cls[b,:] ----------------
// grid 128, block 256 (4 waves). q_cls (64 KB) staged in LDS.
// Each wave handles 2 d-rows; lanes span c (coalesced float4), shuffle-reduce.
__global__ __launch_bounds__(256) void v_kernel(
    const float* __restrict__ w, const float* __restrict__ qcls,
    float* __restrict__ v) {
    __shared__ float qs[BATCH * CH];   // 64 KB
    const int t = threadIdx.x;
    for (int i = t; i < BATCH * CH; i += 256) qs[i] = qcls[i];
    __syncthreads();
    const int lane = t & 63;
    const int wave = t >> 6;
    #pragma unroll
    for (int k = 0; k < 2; ++k) {
        const int d = blockIdx.x * 8 + wave * 2 + k;
        const float* wrow = w + (size_t)d * W3 + CH;    // Wk = cols [1024,2048)
        float4 wv4[4];
        #pragma unroll
        for (int j = 0; j < 4; ++j)
            wv4[j] = *(const float4*)(wrow + lane * 4 + j * 256);
        #pragma unroll
        for (int b = 0; b < BATCH; ++b) {
            float acc = 0.f;
            #pragma unroll
            for (int j = 0; j < 4; ++j) {
                const float4 qv = *(const float4*)(&qs[b * CH + lane * 4 + j * 256]);
                acc += wv4[j].x * qv.x + wv4[j].y * qv.y
                     + wv4[j].z * qv.z + wv4[j].w * qv.w;
            }
            #pragma unroll
            for (int off = 32; off > 0; off >>= 1)
                acc += __shfl_down(acc, off, 64);
            if (lane == 0) v[b * CH + d] = acc;
        }
    }
}

// ---------------- K3: logits (the memory-bound streamer) ----------------
// One wave per (b,n) row: 1024-float dot with v[b]. grid 8192 x 256.
// All 4 rows of a block share one batch (2048 % 4 == 0) -> v[b] staged in LDS.
__global__ __launch_bounds__(256) void logits_kernel(
    const float* __restrict__ x, const float* __restrict__ v,
    float* __restrict__ logits) {
    const int t = threadIdx.x;
    const int lane = t & 63;
    const int row0 = blockIdx.x * 4;
    const int b = row0 >> 11;          // constant within block

    __shared__ float4 vs[CH / 4];      // 4 KB
    vs[t] = ((const float4*)(v + (size_t)b * CH))[t];
    __syncthreads();

    const int row = row0 + (t >> 6);
    const int n = row & (NOUT - 1);
    const float* xrow = x + ((size_t)b * SEQ + n + 1) * CH;
    float acc = 0.f;
    #pragma unroll
    for (int j = 0; j < 4; ++j) {
        const float4 xv = *(const float4*)(xrow + lane * 4 + j * 256);
        const float4 vv = vs[lane + j * 64];
        acc += xv.x * vv.x + xv.y * vv.y + xv.z * vv.z + xv.w * vv.w;
    }
    #pragma unroll
    for (int off = 32; off > 0; off >>= 1)
        acc += __shfl_down(acc, off, 64);
    if (lane == 0) logits[row] = acc * 0.03125f;   // scale = C^-0.5 = 1/32
}

// ---------------- K4: softmax over 2048 per batch ----------------
__global__ __launch_bounds__(256) void softmax_kernel(
    const float* __restrict__ logits, float* __restrict__ out) {
    const int b = blockIdx.x;
    const int t = threadIdx.x;
    __shared__ float sm[256];
    float val[8];
    float m = -1e30f;
    #pragma unroll
    for (int i = 0; i < 8; ++i) {
        val[i] = logits[b * NOUT + t + i * 256];
        m = fmaxf(m, val[i]);
    }
    sm[t] = m; __syncthreads();
    for (int s = 128; s > 0; s >>= 1) {
        if (t < s) sm[t] = fmaxf(sm[t], sm[t + s]);
        __syncthreads();
    }
    const float mx = sm[0];
    __syncthreads();
    float e[8];
    float sum = 0.f;
    #pragma unroll
    for (int i = 0; i < 8; ++i) { e[i] = expf(val[i] - mx); sum += e[i]; }
    sm[t] = sum; __syncthreads();
    for (int s = 128; s > 0; s >>= 1) {
        if (t < s) sm[t] += sm[t + s];
        __syncthreads();
    }
    const float inv = 1.0f / sm[0];
    #pragma unroll
    for (int i = 0; i < 8; ++i) out[b * NOUT + t + i * 256] = e[i] * inv;
}

extern "C" void kernel_launch(void* const* d_in, const int* in_sizes, int n_in,
                              void* d_out, int out_size, void* d_ws, size_t ws_size,
                              hipStream_t stream) {
    const float* x = (const float*)d_in[0];   // (16, 2049, 1024) fp32
    const float* w = (const float*)d_in[1];   // (1024, 3072) fp32
    float* out = (float*)d_out;               // (16, 2048) fp32
    float* ws = (float*)d_ws;

    float* qcls   = ws;                        // 16384 floats
    float* vbuf   = ws + 16384;                // 16384 floats
    float* logits = ws + 32768;                // 32768 floats

    qcls_kernel<<<64, 512, 0, stream>>>(x, w, qcls);
    v_kernel<<<128, 256, 0, stream>>>(w, qcls, vbuf);
    logits_kernel<<<8192, 256, 0, stream>>>(x, vbuf, logits);
    softmax_kernel<<<BATCH, 256, 0, stream>>>(logits, out);
}

// Round 5
// 215.681 us; speedup vs baseline: 6.1940x; 1.0411x over previous
//
#include <hip/hip_runtime.h>
#include <math.h>

// Problem: B=16, N=2049, C=1024, w_qkv is (1024, 3072) row-major.
// out = softmax over n of  scale * (x[b,0,:] @ Wq) . (x[b,n+1,:] @ Wk)
// Reassociated: q_cls[b] = Wq^T x[b,0,:];  v[b] = Wk @ q_cls[b];
//               logit[b,n] = scale * x[b,n+1,:] . v[b]
//
// Lessons so far: dispatch gaps are ~1-2us (graph-captured) -- every fusion
// that traded kernel efficiency for a dispatch LOST (rounds 2,3,4). This
// round returns to the measured-best round-0 5-dispatch structure with
// surgical upgrades only:
//   K1: same tiling/memory pattern, but 4 waves/block (was 1) for latency
//       hiding; 2-phase LDS cross-wave reduce (round-2-verified pattern).
//   K3: v[b] staged in LDS (4KB; block is batch-uniform).
//   K4: wave-shuffle softmax reductions (3 barriers, was 16).

#define BATCH 16
#define SEQ   2049
#define CH    1024
#define W3    3072
#define NOUT  2048

// ws layout (floats):
//   part   : [0, 64*16*1024) = 1048576  (4 MB)
//   qcls   : [1048576, +16384)
//   v      : [1064960, +16384)
//   logits : [1081344, +32768)

// ---------------- K1: q_cls partials ----------------
// grid (4 colchunks, 64 dchunks), block 256 (4 waves).
// Block (ci,pi): Wq tile rows [pi*16,+16) x cols [ci*256,+256).
// Wave w owns rows pi*16 + w*4 + (0..3); per-row load = 64 lanes x float4
// = 1KB coalesced. Wq read exactly once chip-wide (4 MB). 2-phase LDS
// reduce across the 4 waves -> same 64-partial layout as the baseline.
__global__ __launch_bounds__(256) void qcls_partial_kernel(
    const float* __restrict__ x, const float* __restrict__ w,
    float* __restrict__ part) {
    const int ci = blockIdx.x;          // 0..3
    const int pi = blockIdx.y;          // 0..63
    const int t  = threadIdx.x;
    const int lane = t & 63;
    const int wv   = t >> 6;            // 0..3

    __shared__ float  xs[BATCH][16];    // 1 KB: xs[b][dd] = x[b,0,pi*16+dd]
    __shared__ float4 red[4][8][64];    // 32 KB

    {   // 256 threads cover 16x16 exactly
        const int b = t >> 4, dd = t & 15;
        xs[b][dd] = x[(size_t)b * SEQ * CH + pi * 16 + dd];
    }
    __syncthreads();

    const int c = ci * 256 + lane * 4;
    float4 acc[BATCH];
    #pragma unroll
    for (int b = 0; b < BATCH; ++b) acc[b] = {0.f, 0.f, 0.f, 0.f};

    const int drow0 = pi * 16 + wv * 4;
    #pragma unroll
    for (int dd = 0; dd < 4; ++dd) {
        const float4 wvec = *(const float4*)(w + (size_t)(drow0 + dd) * W3 + c);
        const float s0 = xs[0][wv * 4 + dd];   // force xs read order near use
        acc[0].x += s0 * wvec.x; acc[0].y += s0 * wvec.y;
        acc[0].z += s0 * wvec.z; acc[0].w += s0 * wvec.w;
        #pragma unroll
        for (int b = 1; b < BATCH; ++b) {
            const float s = xs[b][wv * 4 + dd];
            acc[b].x += s * wvec.x; acc[b].y += s * wvec.y;
            acc[b].z += s * wvec.z; acc[b].w += s * wvec.w;
        }
    }

    // 2-phase cross-wave reduce; wave w owns batches (w*2, w*2+1) per phase.
    #pragma unroll
    for (int p = 0; p < 2; ++p) {
        __syncthreads();                 // protect prior-phase reads
        #pragma unroll
        for (int b2 = 0; b2 < 8; ++b2)
            red[wv][b2][lane] = acc[p * 8 + b2];
        __syncthreads();
        #pragma unroll
        for (int k = 0; k < 2; ++k) {
            const int b2 = wv * 2 + k;
            float4 s = red[0][b2][lane];
            #pragma unroll
            for (int ww = 1; ww < 4; ++ww) {
                const float4 r = red[ww][b2][lane];
                s.x += r.x; s.y += r.y; s.z += r.z; s.w += r.w;
            }
            *(float4*)(part + ((size_t)pi * BATCH + p * 8 + b2) * CH + c) = s;
        }
    }
}

// ---------------- K2a: reduce 64 partials -> q_cls ----------------
// grid 64, block 256. Thread owns one (b,c); coalesced across c.
__global__ __launch_bounds__(256) void qcls_reduce_kernel(
    const float* __restrict__ part, float* __restrict__ qcls) {
    const int id = blockIdx.x * 256 + threadIdx.x;   // b*1024 + c
    float s = 0.f;
    #pragma unroll 8
    for (int p = 0; p < 64; ++p) s += part[(size_t)p * BATCH * CH + id];
    qcls[id] = s;
}

// ---------------- K2b: v[b,d] = Wk[d,:] . q_cls[b,:] ----------------
// grid 128, block 256 (4 waves). q_cls (64 KB) staged in LDS.
// Each wave handles 2 d-rows; lanes span c (coalesced float4), shuffle-reduce.
__global__ __launch_bounds__(256) void v_kernel(
    const float* __restrict__ w, const float* __restrict__ qcls,
    float* __restrict__ v) {
    __shared__ float qs[BATCH * CH];   // 64 KB
    const int t = threadIdx.x;
    for (int i = t; i < BATCH * CH; i += 256) qs[i] = qcls[i];
    __syncthreads();
    const int lane = t & 63;
    const int wave = t >> 6;
    #pragma unroll
    for (int k = 0; k < 2; ++k) {
        const int d = blockIdx.x * 8 + wave * 2 + k;
        const float* wrow = w + (size_t)d * W3 + CH;    // Wk = cols [1024,2048)
        float4 wv4[4];
        #pragma unroll
        for (int j = 0; j < 4; ++j)
            wv4[j] = *(const float4*)(wrow + lane * 4 + j * 256);
        #pragma unroll
        for (int b = 0; b < BATCH; ++b) {
            float acc = 0.f;
            #pragma unroll
            for (int j = 0; j < 4; ++j) {
                const float4 qv = *(const float4*)(&qs[b * CH + lane * 4 + j * 256]);
                acc += wv4[j].x * qv.x + wv4[j].y * qv.y
                     + wv4[j].z * qv.z + wv4[j].w * qv.w;
            }
            #pragma unroll
            for (int off = 32; off > 0; off >>= 1)
                acc += __shfl_down(acc, off, 64);
            if (lane == 0) v[b * CH + d] = acc;
        }
    }
}

// ---------------- K3: logits (the memory-bound streamer) ----------------
// One wave per (b,n) row: 1024-float dot with v[b]. grid 8192 x 256.
// All 4 rows of a block share one batch (2048 % 4 == 0) -> v[b] in LDS.
__global__ __launch_bounds__(256) void logits_kernel(
    const float* __restrict__ x, const float* __restrict__ v,
    float* __restrict__ logits) {
    const int t = threadIdx.x;
    const int lane = t & 63;
    const int row0 = blockIdx.x * 4;
    const int b = row0 >> 11;          // constant within block

    __shared__ float4 vs[CH / 4];      // 4 KB
    vs[t] = ((const float4*)(v + (size_t)b * CH))[t];
    __syncthreads();

    const int row = row0 + (t >> 6);
    const int n = row & (NOUT - 1);
    const float* xrow = x + ((size_t)b * SEQ + n + 1) * CH;
    float acc = 0.f;
    #pragma unroll
    for (int j = 0; j < 4; ++j) {
        const float4 xv = *(const float4*)(xrow + lane * 4 + j * 256);
        const float4 vv = vs[lane + j * 64];
        acc += xv.x * vv.x + xv.y * vv.y + xv.z * vv.z + xv.w * vv.w;
    }
    #pragma unroll
    for (int off = 32; off > 0; off >>= 1)
        acc += __shfl_down(acc, off, 64);
    if (lane == 0) logits[row] = acc * 0.03125f;   // scale = C^-0.5 = 1/32
}

// ---------------- K4: softmax over 2048 per batch ----------------
// 256 threads = 4 waves; shuffle reduce within wave, tiny LDS across waves.
__global__ __launch_bounds__(256) void softmax_kernel(
    const float* __restrict__ logits, float* __restrict__ out) {
    const int b = blockIdx.x;
    const int t = threadIdx.x;
    const int lane = t & 63;
    const int wv = t >> 6;
    __shared__ float wred[4];

    float val[8];
    float m = -1e30f;
    #pragma unroll
    for (int i = 0; i < 8; ++i) {
        val[i] = logits[b * NOUT + t + i * 256];
        m = fmaxf(m, val[i]);
    }
    #pragma unroll
    for (int off = 32; off > 0; off >>= 1)
        m = fmaxf(m, __shfl_xor(m, off, 64));
    if (lane == 0) wred[wv] = m;
    __syncthreads();
    const float mx = fmaxf(fmaxf(wred[0], wred[1]), fmaxf(wred[2], wred[3]));
    __syncthreads();                    // before wred reuse

    float e[8];
    float sum = 0.f;
    #pragma unroll
    for (int i = 0; i < 8; ++i) { e[i] = expf(val[i] - mx); sum += e[i]; }
    #pragma unroll
    for (int off = 32; off > 0; off >>= 1)
        sum += __shfl_xor(sum, off, 64);
    if (lane == 0) wred[wv] = sum;
    __syncthreads();
    const float inv = 1.0f / (wred[0] + wred[1] + wred[2] + wred[3]);
    #pragma unroll
    for (int i = 0; i < 8; ++i) out[b * NOUT + t + i * 256] = e[i] * inv;
}

extern "C" void kernel_launch(void* const* d_in, const int* in_sizes, int n_in,
                              void* d_out, int out_size, void* d_ws, size_t ws_size,
                              hipStream_t stream) {
    const float* x = (const float*)d_in[0];   // (16, 2049, 1024) fp32
    const float* w = (const float*)d_in[1];   // (1024, 3072) fp32
    float* out = (float*)d_out;               // (16, 2048) fp32
    float* ws = (float*)d_ws;

    float* part   = ws;                        // 1,048,576 floats (4 MB)
    float* qcls   = ws + 1048576;              // 16384 floats
    float* vbuf   = ws + 1048576 + 16384;      // 16384 floats
    float* logits = ws + 1048576 + 32768;      // 32768 floats

    qcls_partial_kernel<<<dim3(4, 64), 256, 0, stream>>>(x, w, part);
    qcls_reduce_kernel<<<64, 256, 0, stream>>>(part, qcls);
    v_kernel<<<128, 256, 0, stream>>>(w, qcls, vbuf);
    logits_kernel<<<8192, 256, 0, stream>>>(x, vbuf, logits);
    softmax_kernel<<<BATCH, 256, 0, stream>>>(logits, out);
}